// Round 7
// baseline (178.388 us; speedup 1.0000x reference)
//
#include <hip/hip_runtime.h>
#include <hip/hip_fp16.h>

#define EDGES   262144
#define CTPB    256
#define SCHUNK  256
#define NINT    2048   // 32 rblocks * 8 schunks * 8 segments
#define NFLT    (EDGES / CTPB)   // 1024
#define NPRI    16     // 4096 nodes / 256
#define NBLK    (NINT + NFLT + NPRI)

// Inputs pre-scaled by KS = sqrt(log2 e): exp arg is in log2 units (raw exp2),
// erf poly coefficients absorb the argument scale, output scale sqrt(L) folded
// into the final constant.
#define KS      1.2011224087864498f
#define SCLAMP  0.000244140625f   // 2^-12, exact in f16

// erf_s(x) = erf(x / sqrt(log2e)) poly coefficients
#define EC0  0.93905091f
#define EC1 -0.21365741f
#define EC2  0.04006996f
#define EC3 -0.00458728f
#define EC4  0.00023054f
#define ECL  2.4022448f           // clamp: 2*sqrt(log2 e)

typedef _Float16 v2h __attribute__((ext_vector_type(2)));

// ROCm 7.2 hip_fp16.h lacks __hmax2/__hmin2 — build packed min/max ourselves.
__device__ __forceinline__ __half2 hmax2(__half2 a, __half2 b) {
    v2h x = __builtin_bit_cast(v2h, a), y = __builtin_bit_cast(v2h, b);
    return __builtin_bit_cast(__half2, __builtin_elementwise_max(x, y));
}
__device__ __forceinline__ __half2 hmin2(__half2 a, __half2 b) {
    v2h x = __builtin_bit_cast(v2h, a), y = __builtin_bit_cast(v2h, b);
    return __builtin_bit_cast(__half2, __builtin_elementwise_min(x, y));
}

__device__ __forceinline__ float fdot2_acc(__half2 q, float acc) {
#if defined(__has_builtin) && __has_builtin(__builtin_amdgcn_fdot2)
    v2h a = __builtin_bit_cast(v2h, q);
    v2h ones = {(_Float16)1.0f, (_Float16)1.0f};
    return __builtin_amdgcn_fdot2(a, ones, acc, false);
#else
    return acc + __low2float(q) + __high2float(q);
#endif
}

struct alignas(16) SP { __half2 zx, zy, dx, dy; };   // 2 senders per entry

template <int NW>
__device__ __forceinline__ float block_reduce(float v, float* sm) {
    #pragma unroll
    for (int o = 32; o > 0; o >>= 1) v += __shfl_down(v, o, 64);
    int lane = threadIdx.x & 63;
    int wid  = threadIdx.x >> 6;
    if (lane == 0) sm[wid] = v;
    __syncthreads();
    float r = 0.0f;
    if (threadIdx.x == 0) {
        #pragma unroll
        for (int w = 0; w < NW; ++w) r += sm[w];
    }
    return r;
}

// Packed 2-pair term. Per 2 pairs: ~36 pk ops + 4 f16 trans + 1 dot2.
__device__ __forceinline__ float pair2(const SP s, __half2 rzx, __half2 rzy,
                                       __half2 rdx, __half2 rdy,
                                       __half2 scl, __half2 cl, __half2 ncl,
                                       __half2 c4, __half2 c3, __half2 c2,
                                       __half2 c1, __half2 c0, float acc) {
    __half2 wx = __hsub2(s.zx, rzx);
    __half2 wy = __hsub2(s.zy, rzy);
    __half2 vx = __hsub2(s.dx, rdx);
    __half2 vy = __hsub2(s.dy, rdy);
    __half2 D  = __hfma2(wy, wy, __hmul2(wx, wx));
    __half2 S  = __hfma2(vy, vy, __hmul2(vx, vx));
    __half2 mc = __hfma2(vy, wy, __hmul2(vx, wx));   // <v,w> = -C
    __half2 Sc = hmax2(S, scl);
    __half2 rsq = h2rsqrt(Sc);
    __half2 g  = __hmul2(mc, rsq);                   // -u
    __half2 rt = __hmul2(Sc, rsq);                   // sqrt(Sc)
    __half2 gg = __hmul2(g, g);
    __half2 ea = __hsub2(gg, D);                     // u^2 - D (log2 units)
    __half2 ex = h2exp2(ea);
    __half2 a  = hmin2(hmax2(__hadd2(rt, g), ncl), cl);
    __half2 gc = hmin2(hmax2(g, ncl), cl);
    __half2 ta = __hmul2(a, a);
    __half2 pa = __hfma2(ta, c4, c3);
    pa = __hfma2(ta, pa, c2);
    pa = __hfma2(ta, pa, c1);
    pa = __hfma2(ta, pa, c0);
    __half2 Ea = __hmul2(a, pa);
    __half2 tg = __hmul2(gc, gc);
    __half2 pg = __hfma2(tg, c4, c3);
    pg = __hfma2(tg, pg, c2);
    pg = __hfma2(tg, pg, c1);
    pg = __hfma2(tg, pg, c0);
    __half2 Eg = __hmul2(gc, pg);
    __half2 e  = __hsub2(Ea, Eg);
    __half2 q  = __hmul2(__hmul2(ex, rsq), e);
    return fdot2_acc(q, acc);
}

// Single dispatch. ws layout: u32 counter @0, float acc[3] @16 (memset 32 B).
// Blocks [0,NINT): integral; [NINT,+NFLT): edge term; rest: prior.
// Last finishing block reduces acc[] and writes the output.
__global__ __launch_bounds__(CTPB) void k_all(const float* __restrict__ Z,
        const float* __restrict__ ts, const int* __restrict__ snd,
        const int* __restrict__ rcv, const int* __restrict__ nodes,
        const int* __restrict__ su, const float* __restrict__ cp,
        const float* __restrict__ betap, unsigned* __restrict__ ws,
        float* __restrict__ out, float n_entries, float bs) {
    __shared__ SP sp[SCHUNK / 2];
    __shared__ float smr[CTPB / 64];
    __shared__ int isLast;
    float* acc = (float*)(ws + 4);
    const int bid = blockIdx.x;
    const int tid = threadIdx.x;
    float r;
    int slot;

    const __half2 scl = __half2half2(__float2half(SCLAMP));
    const __half2 cl  = __half2half2(__float2half(ECL));
    const __half2 ncl = __half2half2(__float2half(-ECL));
    const __half2 c4  = __half2half2(__float2half(EC4));
    const __half2 c3  = __half2half2(__float2half(EC3));
    const __half2 c2  = __half2half2(__float2half(EC2));
    const __half2 c1  = __half2half2(__float2half(EC1));
    const __half2 c0  = __half2half2(__float2half(EC0));

    if (bid < NINT) {
        const int k  = bid >> 8;
        const int sc = (bid >> 5) & 7;
        const int rb = bid & 31;
        {   // stage sender chunk as f16 (conversion forms MUST match receiver)
            int n = su[sc * SCHUNK + tid];
            const float* z = Z + n * 18 + k;
            float zx = z[0] * KS, zy = z[9] * KS;
            float dx = fmaf(z[1],  KS, -zx);
            float dy = fmaf(z[10], KS, -zy);
            __half* b = (__half*)sp + (tid >> 1) * 8 + (tid & 1);
            b[0] = __float2half(zx);
            b[2] = __float2half(zy);
            b[4] = __float2half(dx);
            b[6] = __float2half(dy);
        }
        const float* zr = Z + (rb * CTPB + tid) * 18 + k;
        float rzxf = zr[0] * KS, rzyf = zr[9] * KS;
        float rdxf = fmaf(zr[1],  KS, -rzxf);
        float rdyf = fmaf(zr[10], KS, -rzyf);
        __half2 rzx = __half2half2(__float2half(rzxf));
        __half2 rzy = __half2half2(__float2half(rzyf));
        __half2 rdx = __half2half2(__float2half(rdxf));
        __half2 rdy = __half2half2(__float2half(rdyf));
        __syncthreads();

        float s0 = 0.0f, s1 = 0.0f;
        #pragma unroll 4
        for (int i = 0; i < SCHUNK / 2; i += 2) {
            s0 = pair2(sp[i],     rzx, rzy, rdx, rdy, scl, cl, ncl, c4, c3, c2, c1, c0, s0);
            s1 = pair2(sp[i + 1], rzx, rzy, rdx, rdy, scl, cl, ncl, c4, c3, c2, c1, c0, s1);
        }
        r = block_reduce<CTPB / 64>(s0 + s1, smr);
        slot = 2;
    } else if (bid < NINT + NFLT) {
        // ---- edge likelihood: -|od*(Zs_c-Zr_c) + d*(Zs_n-Zr_n)|^2  (f32) ----
        int e = (bid - NINT) * CTPB + tid;
        float seg = cp[1] - cp[0];
        float x   = ts[e] / seg;
        float kf  = floorf(x);
        int kappa = (int)kf;
        float d   = x - kf;
        float od  = 1.0f - d;
        int sb = snd[e] * 18, rbse = rcv[e] * 18;
        float ux = Z[sb + kappa]     - Z[rbse + kappa];
        float uy = Z[sb + 9 + kappa] - Z[rbse + 9 + kappa];
        float vx = Z[sb + kappa + 1]     - Z[rbse + kappa + 1];
        float vy = Z[sb + 9 + kappa + 1] - Z[rbse + 9 + kappa + 1];
        float wx = od * ux + d * vx;
        float wy = od * uy + d * vy;
        r = block_reduce<CTPB / 64>(-fmaf(wx, wx, wy * wy), smr);
        slot = 1;
    } else {
        // ---- prior (f32) ----
        int i = (bid - NINT - NFLT) * CTPB + tid;
        int n = nodes[i];
        const float* z = Z + n * 18;
        float s = 0.0f;
        #pragma unroll
        for (int d = 0; d < 2; ++d) {
            float prev = z[d * 9];
            s = fmaf(prev, prev, s);
            #pragma unroll
            for (int k = 1; k <= 8; ++k) {
                float cur = z[d * 9 + k];
                float df  = cur - prev;
                s = fmaf(df, df, s);
                prev = cur;
            }
        }
        r = block_reduce<CTPB / 64>(s, smr);
        slot = 0;
    }

    if (tid == 0) {
        atomicAdd(acc + slot, r);
        __threadfence();
        unsigned old = atomicAdd(ws, 1u);
        isLast = (old == NBLK - 1);
    }
    __syncthreads();
    if (isLast && tid == 0) {
        __threadfence();
        float pr = acc[0], fl = acc[1], qq = acc[2];
        // Remove the 16384 reference-masked self-pairs (w=v=0 bit-exactly,
        // since sender and receiver convert the same f32 values): run the
        // IDENTICAL pair2 op sequence on zero inputs. The call covers 2
        // self-pairs (both halves), so subtract 8192x.
        SP z0; __half2 h0 = __half2half2(__float2half(0.0f));
        z0.zx = h0; z0.zy = h0; z0.dx = h0; z0.dy = h0;
        float qself2 = pair2(z0, h0, h0, h0, h0, scl, cl, ncl,
                             c4, c3, c2, c1, c0, 0.0f);
        double Q = (double)qq - 8192.0 * (double)qself2;

        float prior = 10.0f * pr;
        float beta  = betap[0];
        float seg   = cp[1] - cp[0];
        // integral = 0.5(scan)*0.5(erf pair)*sqrt(0.5)(sigma)*dt * Q * sqrt(L)
        const double CQ = 0.17677669529663687 * 1.2011224087864498;
        float integral = (float)(CQ * (double)seg * Q);
        const float sqrt2pi = 2.5066282746310002f;
        float res = prior - beta * n_entries - fl + sqrt2pi * expf(beta) * integral;
        out[0] = (8192.0f / bs) * res;
    }
}

extern "C" void kernel_launch(void* const* d_in, const int* in_sizes, int n_in,
                              void* d_out, int out_size, void* d_ws, size_t ws_size,
                              hipStream_t stream) {
    const float* Z    = (const float*)d_in[0];
    const float* beta = (const float*)d_in[1];
    const float* ts   = (const float*)d_in[2];
    const int*   snd  = (const int*)d_in[3];
    const int*   rcv  = (const int*)d_in[4];
    const int*   nodes= (const int*)d_in[5];
    const int*   su   = (const int*)d_in[6];
    const float* cp   = (const float*)d_in[7];

    (void)hipMemsetAsync(d_ws, 0, 32, stream);
    k_all<<<NBLK, CTPB, 0, stream>>>(Z, ts, snd, rcv, nodes, su, cp, beta,
                                     (unsigned*)d_ws, (float*)d_out,
                                     (float)in_sizes[2], (float)in_sizes[5]);
}